// Round 1
// baseline (866.007 us; speedup 1.0000x reference)
//
#include <hip/hip_runtime.h>

// LSTM: T=1024 steps, B=32768 independent batch lanes, I=1, H=3.
// One thread per batch element; h[3], c[3] live in registers; weights are
// wave-uniform (compiler scalarizes to SGPRs). Only serial dep is over T.

constexpr int T_STEPS = 1024;
constexpr int BATCH   = 32768;
constexpr int HID     = 3;
constexpr int G4      = 4 * HID;   // 12 gate rows

__device__ __forceinline__ float fsigmoid(float z) {
    // 1 / (1 + 2^(-z*log2e)) ; exp2/rcp are HW approx (~1e-7 rel), threshold 2e-2
    float e = __builtin_amdgcn_exp2f(-1.4426950408889634f * z);
    return __builtin_amdgcn_rcpf(1.0f + e);
}
__device__ __forceinline__ float ftanh(float z) {
    // 1 - 2/(2^(2z*log2e) + 1) ; saturates correctly at +/-inf
    float e = __builtin_amdgcn_exp2f(2.8853900817779268f * z);
    return 1.0f - 2.0f * __builtin_amdgcn_rcpf(e + 1.0f);
}

__global__ __launch_bounds__(64) void lstm_seq_kernel(
    const float* __restrict__ x,     // [T, B, 1]
    const float* __restrict__ h0,    // [B, 3]
    const float* __restrict__ c0,    // [B, 3]
    const float* __restrict__ W_ih,  // [12, 1]
    const float* __restrict__ W_hh,  // [12, 3]
    const float* __restrict__ b_ih,  // [12]
    const float* __restrict__ b_hh,  // [12]
    float* __restrict__ out)         // [T, B, 3]
{
    const int b = blockIdx.x * blockDim.x + threadIdx.x;
    if (b >= BATCH) return;

    // Wave-uniform weights: uniform addresses -> s_load, held in SGPRs.
    float wi[G4], bias[G4], wh[G4][HID];
#pragma unroll
    for (int r = 0; r < G4; ++r) {
        wi[r]   = W_ih[r];
        bias[r] = b_ih[r] + b_hh[r];
#pragma unroll
        for (int j = 0; j < HID; ++j) wh[r][j] = W_hh[r * HID + j];
    }

    float h[HID], c[HID];
#pragma unroll
    for (int j = 0; j < HID; ++j) {
        h[j] = h0[b * HID + j];
        c[j] = c0[b * HID + j];
    }

    // Prefetch x one step ahead; x-load doesn't depend on the recurrence.
    float xv = x[b];
    for (int t = 0; t < T_STEPS; ++t) {
        const int tn = (t + 1 < T_STEPS) ? (t + 1) : (T_STEPS - 1);
        const float xnext = x[tn * BATCH + b];

        // Gate pre-activations: pre[r] = x*wi[r] + bias[r] + W_hh[r,:]·h
        float pre[G4];
#pragma unroll
        for (int r = 0; r < G4; ++r) {
            float v = fmaf(xv, wi[r], bias[r]);
            v = fmaf(h[0], wh[r][0], v);
            v = fmaf(h[1], wh[r][1], v);
            v = fmaf(h[2], wh[r][2], v);
            pre[r] = v;
        }

        // PyTorch gate order: i=[0:3), f=[3:6), g=[6:9), o=[9:12)
#pragma unroll
        for (int j = 0; j < HID; ++j) {
            float ig = fsigmoid(pre[j]);
            float fg = fsigmoid(pre[HID + j]);
            float gg = ftanh(pre[2 * HID + j]);
            float og = fsigmoid(pre[3 * HID + j]);
            c[j] = fmaf(fg, c[j], ig * gg);
            h[j] = og * ftanh(c[j]);
        }

        const int obase = (t * BATCH + b) * HID;
        out[obase + 0] = h[0];
        out[obase + 1] = h[1];
        out[obase + 2] = h[2];

        xv = xnext;
    }
}

extern "C" void kernel_launch(void* const* d_in, const int* in_sizes, int n_in,
                              void* d_out, int out_size, void* d_ws, size_t ws_size,
                              hipStream_t stream) {
    const float* x    = (const float*)d_in[0];
    const float* h0   = (const float*)d_in[1];
    const float* c0   = (const float*)d_in[2];
    const float* W_ih = (const float*)d_in[3];
    const float* W_hh = (const float*)d_in[4];
    const float* b_ih = (const float*)d_in[5];
    const float* b_hh = (const float*)d_in[6];
    float* out = (float*)d_out;

    // block=64 -> 512 single-wave blocks -> every CU gets ~2 waves.
    dim3 grid(BATCH / 64), block(64);
    lstm_seq_kernel<<<grid, block, 0, stream>>>(x, h0, c0, W_ih, W_hh, b_ih, b_hh, out);
}

// Round 2
// 700.687 us; speedup vs baseline: 1.2359x; 1.2359x over previous
//
#include <hip/hip_runtime.h>

// LSTM: T=1024 steps, B=32768 independent batch lanes, I=1, H=3.
// One thread per batch element; h[3], c[3] in registers; weights wave-uniform.
// R1 fix: x was prefetched only 1 step ahead -> every step ate ~900 cyc of HBM
// latency (measured: 1172 cyc/step, VALUBusy 26%). Now prefetch NB=16 x values
// per chunk, double-buffered in registers: next chunk's 16 loads are issued ~16
// steps before first use, amortizing latency 16x.

constexpr int T_STEPS = 1024;
constexpr int BATCH   = 32768;
constexpr int HID     = 3;
constexpr int G4      = 4 * HID;   // 12 gate rows
constexpr int NB      = 16;        // x prefetch chunk (registers)

__device__ __forceinline__ float fsigmoid(float z) {
    float e = __builtin_amdgcn_exp2f(-1.4426950408889634f * z);
    return __builtin_amdgcn_rcpf(1.0f + e);
}
__device__ __forceinline__ float ftanh(float z) {
    float e = __builtin_amdgcn_exp2f(2.8853900817779268f * z);
    return 1.0f - 2.0f * __builtin_amdgcn_rcpf(e + 1.0f);
}

__global__ __launch_bounds__(64) void lstm_seq_kernel(
    const float* __restrict__ x,     // [T, B, 1]
    const float* __restrict__ h0,    // [B, 3]
    const float* __restrict__ c0,    // [B, 3]
    const float* __restrict__ W_ih,  // [12, 1]
    const float* __restrict__ W_hh,  // [12, 3]
    const float* __restrict__ b_ih,  // [12]
    const float* __restrict__ b_hh,  // [12]
    float* __restrict__ out)         // [T, B, 3]
{
    const int b = blockIdx.x * blockDim.x + threadIdx.x;
    if (b >= BATCH) return;

    // Wave-uniform weights -> scalar loads, held in SGPRs.
    float wi[G4], bias[G4], wh[G4][HID];
#pragma unroll
    for (int r = 0; r < G4; ++r) {
        wi[r]   = W_ih[r];
        bias[r] = b_ih[r] + b_hh[r];
#pragma unroll
        for (int j = 0; j < HID; ++j) wh[r][j] = W_hh[r * HID + j];
    }

    float h[HID], c[HID];
#pragma unroll
    for (int j = 0; j < HID; ++j) {
        h[j] = h0[b * HID + j];
        c[j] = c0[b * HID + j];
    }

    // Prime the first chunk of x.
    float cur[NB], nxt[NB];
#pragma unroll
    for (int i = 0; i < NB; ++i) cur[i] = x[i * BATCH + b];

    for (int chunk = 0; chunk < T_STEPS / NB; ++chunk) {
        // Issue next chunk's loads now; first use is NB steps away.
        const int base_next = (chunk + 1) * NB;
#pragma unroll
        for (int i = 0; i < NB; ++i) {
            int tl = base_next + i;
            if (tl >= T_STEPS) tl = T_STEPS - 1;   // harmless duplicate on last chunk
            nxt[i] = x[tl * BATCH + b];
        }

#pragma unroll
        for (int i = 0; i < NB; ++i) {
            const int t = chunk * NB + i;
            const float xv = cur[i];

            // Gate pre-activations: pre[r] = x*wi[r] + bias[r] + W_hh[r,:]·h
            float pre[G4];
#pragma unroll
            for (int r = 0; r < G4; ++r) {
                float v = fmaf(xv, wi[r], bias[r]);
                v = fmaf(h[0], wh[r][0], v);
                v = fmaf(h[1], wh[r][1], v);
                v = fmaf(h[2], wh[r][2], v);
                pre[r] = v;
            }

            // PyTorch gate order: i=[0:3), f=[3:6), g=[6:9), o=[9:12)
#pragma unroll
            for (int j = 0; j < HID; ++j) {
                float ig = fsigmoid(pre[j]);
                float fg = fsigmoid(pre[HID + j]);
                float gg = ftanh(pre[2 * HID + j]);
                float og = fsigmoid(pre[3 * HID + j]);
                c[j] = fmaf(fg, c[j], ig * gg);
                h[j] = og * ftanh(c[j]);
            }

            const int obase = (t * BATCH + b) * HID;
            out[obase + 0] = h[0];
            out[obase + 1] = h[1];
            out[obase + 2] = h[2];
        }

#pragma unroll
        for (int i = 0; i < NB; ++i) cur[i] = nxt[i];
    }
}

extern "C" void kernel_launch(void* const* d_in, const int* in_sizes, int n_in,
                              void* d_out, int out_size, void* d_ws, size_t ws_size,
                              hipStream_t stream) {
    const float* x    = (const float*)d_in[0];
    const float* h0   = (const float*)d_in[1];
    const float* c0   = (const float*)d_in[2];
    const float* W_ih = (const float*)d_in[3];
    const float* W_hh = (const float*)d_in[4];
    const float* b_ih = (const float*)d_in[5];
    const float* b_hh = (const float*)d_in[6];
    float* out = (float*)d_out;

    // block=64 -> 512 single-wave blocks -> 2 waves per CU across all 256 CUs.
    dim3 grid(BATCH / 64), block(64);
    lstm_seq_kernel<<<grid, block, 0, stream>>>(x, h0, c0, W_ih, W_hh, b_ih, b_hh, out);
}